// Round 3
// baseline (680.753 us; speedup 1.0000x reference)
//
#include <hip/hip_runtime.h>

#define DIM   1024
#define HID   2048
#define NE    8
#define T_TOK 4096

typedef __attribute__((ext_vector_type(8))) short short8;
typedef __attribute__((ext_vector_type(4))) float f32x4;

__device__ __forceinline__ ushort f2bf(float f) {
    union { float f; unsigned u; } v; v.f = f;
    unsigned r = v.u + 0x7FFFu + ((v.u >> 16) & 1u);   // RNE
    return (ushort)(r >> 16);
}

__device__ __forceinline__ float gelu_exact(float x) {
    return 0.5f * x * (1.0f + erff(x * 0.70710678118654752f));
}

// ---------------- convert x (fp32 -> bf16) ----------------
__global__ void convert_x(const float* __restrict__ in, ushort* __restrict__ out, int n8) {
    int i = blockIdx.x * blockDim.x + threadIdx.x;
    if (i >= n8) return;
    const float4* p = (const float4*)in + (size_t)i * 2;
    float4 a = p[0], b = p[1];
    short8 o;
    o[0] = (short)f2bf(a.x); o[1] = (short)f2bf(a.y);
    o[2] = (short)f2bf(a.z); o[3] = (short)f2bf(a.w);
    o[4] = (short)f2bf(b.x); o[5] = (short)f2bf(b.y);
    o[6] = (short)f2bf(b.z); o[7] = (short)f2bf(b.w);
    *(short8*)(out + (size_t)i * 8) = o;
}

// ------------- transpose+convert: in[E][R][C] f32 -> out[E][C][R] bf16 -------------
// 32(C) x 64(R) tile; writes are 64 lanes x 2B = 128B contiguous.
__global__ void transpose_conv(const float* __restrict__ in, ushort* __restrict__ out,
                               int R, int C) {
    __shared__ float tile[32][65];
    size_t eoff = (size_t)blockIdx.z * R * C;
    in += eoff; out += eoff;
    int c0 = blockIdx.x * 32, r0 = blockIdx.y * 64;
    int tx = threadIdx.x & 31, ty = threadIdx.x >> 5;   // 256 threads
#pragma unroll
    for (int rr = 0; rr < 64; rr += 8)
        tile[tx][rr + ty] = in[(size_t)(r0 + rr + ty) * C + (c0 + tx)];
    __syncthreads();
    int lane = threadIdx.x & 63, q = threadIdx.x >> 6;
#pragma unroll
    for (int j = 0; j < 8; ++j) {
        int cc = q * 8 + j;
        out[(size_t)(c0 + cc) * R + (r0 + lane)] = f2bf(tile[cc][lane]);
    }
}

// ---------------- router: top-2 of softmax(x @ rw + rb), renormalized ----------------
__global__ void router_kernel(const float* __restrict__ x, const float* __restrict__ rw,
                              const float* __restrict__ rb, int* __restrict__ cnt,
                              int* __restrict__ ids, float* __restrict__ wts) {
    int wave = threadIdx.x >> 6;
    int lane = threadIdx.x & 63;
    int t = blockIdx.x * 4 + wave;
    const float* xr = x + (size_t)t * DIM;
    float acc[NE];
#pragma unroll
    for (int e = 0; e < NE; ++e) acc[e] = 0.f;
    for (int d = lane; d < DIM; d += 64) {
        float xv = xr[d];
#pragma unroll
        for (int e = 0; e < NE; ++e) acc[e] += xv * rw[d * NE + e];
    }
#pragma unroll
    for (int e = 0; e < NE; ++e) {
#pragma unroll
        for (int off = 32; off; off >>= 1) acc[e] += __shfl_xor(acc[e], off);
    }
    if (lane == 0) {
        float l[NE];
#pragma unroll
        for (int e = 0; e < NE; ++e) l[e] = acc[e] + rb[e];
        int i1 = 0;
#pragma unroll
        for (int e = 1; e < NE; ++e) if (l[e] > l[i1]) i1 = e;
        int i2 = (i1 == 0) ? 1 : 0;
#pragma unroll
        for (int e = 0; e < NE; ++e) if (e != i1 && l[e] > l[i2]) i2 = e;
        float p2 = __expf(l[i2] - l[i1]);      // p1 = 1
        float w1 = 1.0f / (1.0f + p2);
        float w2 = p2 / (1.0f + p2);
        int pos1 = atomicAdd(&cnt[i1], 1);
        ids[i1 * T_TOK + pos1] = t; wts[i1 * T_TOK + pos1] = w1;
        int pos2 = atomicAdd(&cnt[i2], 1);
        ids[i2 * T_TOK + pos2] = t; wts[i2 * T_TOK + pos2] = w2;
    }
}

__global__ void offsets_kernel(const int* __restrict__ cnt, int* __restrict__ offs) {
    if (threadIdx.x == 0) {
        int s = 0;
        for (int e = 0; e < NE; ++e) { offs[e] = s; s += cnt[e]; }
    }
}

// ============ 256x256 tile, BK=64, 8 waves (2Mx4N), double-buffered LDS ============
// LDS: 2 buffers x (A 256x64 + B 256x64) bf16 = 128 KiB (dynamic).
// Layout: [row][64] with element-column XOR swizzle ((row&7)<<3), applied on the
// GLOBAL source column so global_load_lds destinations stay linear.
// Schedule: minimum 2-phase — STAGE(next) issued BEFORE COMPUTE(cur); one
// vmcnt(0)+barrier per K-tile.
__device__ __forceinline__ void mma256(
    const ushort* __restrict__ A, const int* __restrict__ gather, int count,
    const ushort* __restrict__ BT, int K, int tileM, int tileN,
    ushort* lds, f32x4 acc[8][4])
{
    const int tid  = threadIdx.x;
    const int lane = tid & 63, wave = tid >> 6;       // 8 waves
    const int wr = wave >> 2, wc = wave & 3;          // 2M x 4N
    const int g = lane >> 4, fr = lane & 15;
    const int sub = lane >> 3;                        // row within 8-row chunk
    const int kcs = ((lane & 7) ^ sub) << 3;          // pre-swizzled global col

    const ushort* asrc[4];
    const ushort* bsrc[4];
#pragma unroll
    for (int i = 0; i < 4; ++i) {
        int row = (wave * 4 + i) * 8 + sub;           // 32 chunks cover 256 rows
        int ar = tileM + row; if (ar > count - 1) ar = count - 1;
        int grow = gather ? gather[ar] : ar;
        asrc[i] = A  + (size_t)grow * K + kcs;
        bsrc[i] = BT + (size_t)(tileN + row) * K + kcs;
    }

    auto STAGE = [&](int buf, int t) {
#pragma unroll
        for (int i = 0; i < 4; ++i) {
            int chunk = wave * 4 + i;
            __builtin_amdgcn_global_load_lds(
                (const __attribute__((address_space(1))) void*)(asrc[i] + t * 64),
                (__attribute__((address_space(3))) void*)(lds + buf * 32768 + chunk * 512),
                16, 0, 0);
            __builtin_amdgcn_global_load_lds(
                (const __attribute__((address_space(1))) void*)(bsrc[i] + t * 64),
                (__attribute__((address_space(3))) void*)(lds + buf * 32768 + 16384 + chunk * 512),
                16, 0, 0);
        }
    };

    auto COMPUTE = [&](int buf) {
        const ushort* A_s = lds + buf * 32768;
        const ushort* B_s = A_s + 16384;
#pragma unroll
        for (int kk = 0; kk < 2; ++kk) {
            int koff = kk * 32 + g * 8;
            short8 a[8], b[4];
#pragma unroll
            for (int m = 0; m < 8; ++m) {
                int row = wr * 128 + m * 16 + fr;
                a[m] = *(const short8*)&A_s[row * 64 + (koff ^ ((row & 7) << 3))];
            }
#pragma unroll
            for (int n = 0; n < 4; ++n) {
                int col = wc * 64 + n * 16 + fr;
                b[n] = *(const short8*)&B_s[col * 64 + (koff ^ ((col & 7) << 3))];
            }
#pragma unroll
            for (int m = 0; m < 8; ++m)
#pragma unroll
                for (int n = 0; n < 4; ++n)
                    acc[m][n] = __builtin_amdgcn_mfma_f32_16x16x32_bf16(
                        a[m], b[n], acc[m][n], 0, 0, 0);
        }
    };

    const int NT = K >> 6;                            // 16 or 32 (even)
    STAGE(0, 0);
    asm volatile("s_waitcnt vmcnt(0)" ::: "memory");
    __syncthreads();
    for (int t = 0; t < NT - 2; t += 2) {
        STAGE(1, t + 1);
        COMPUTE(0);
        asm volatile("s_waitcnt vmcnt(0)" ::: "memory");
        __syncthreads();
        STAGE(0, t + 2);
        COMPUTE(1);
        asm volatile("s_waitcnt vmcnt(0)" ::: "memory");
        __syncthreads();
    }
    STAGE(1, NT - 1);
    COMPUTE(0);
    asm volatile("s_waitcnt vmcnt(0)" ::: "memory");
    __syncthreads();
    COMPUTE(1);
}

// ---------------- GEMM1: h = gelu(X @ W1 + b1), packed per expert ----------------
__global__ __launch_bounds__(512, 2)
void gemm1_kernel(const ushort* __restrict__ xb,
                  const ushort* __restrict__ ew1T, const ushort* __restrict__ sw1T,
                  const float* __restrict__ eb1, const float* __restrict__ sb1,
                  const int* __restrict__ ids, const int* __restrict__ cnt,
                  const int* __restrict__ offs, ushort* __restrict__ h)
{
    extern __shared__ ushort lds[];
    int e = blockIdx.z;
    int count, hbase;
    const ushort* BT; const float* bias; const int* gather;
    if (e < NE) {
        count  = cnt[e];
        BT     = ew1T + (size_t)e * HID * DIM;
        bias   = eb1 + e * HID;
        gather = ids + e * T_TOK;
        hbase  = T_TOK + offs[e];
    } else {
        count = T_TOK; BT = sw1T; bias = sb1; gather = nullptr; hbase = 0;
    }
    int tileM = blockIdx.y * 256, tileN = blockIdx.x * 256;
    if (tileM >= count) return;

    f32x4 acc[8][4];
#pragma unroll
    for (int m = 0; m < 8; ++m)
#pragma unroll
        for (int n = 0; n < 4; ++n) acc[m][n] = (f32x4){0.f, 0.f, 0.f, 0.f};

    mma256(xb, gather, count, BT, DIM, tileM, tileN, lds, acc);

    const int lane = threadIdx.x & 63, wave = threadIdx.x >> 6;
    const int wr = wave >> 2, wc = wave & 3, g = lane >> 4, fr = lane & 15;
#pragma unroll
    for (int n = 0; n < 4; ++n) {
        int col = tileN + wc * 64 + n * 16 + fr;
        float bc = bias[col];
#pragma unroll
        for (int m = 0; m < 8; ++m) {
#pragma unroll
            for (int i = 0; i < 4; ++i) {
                int row = tileM + wr * 128 + m * 16 + g * 4 + i;
                if (row < count)
                    h[(size_t)(hbase + row) * HID + col] =
                        f2bf(gelu_exact(acc[m][n][i] + bc));
            }
        }
    }
}

// ---------------- GEMM2: Y = H @ W2 + b2 ----------------
// mode 0: shared expert -> plain store (covers all of out, no memset needed)
// mode 1: routed experts -> atomicAdd(w * y)
__global__ __launch_bounds__(512, 2)
void gemm2_kernel(const ushort* __restrict__ h,
                  const ushort* __restrict__ ew2T, const ushort* __restrict__ sw2T,
                  const float* __restrict__ eb2, const float* __restrict__ sb2,
                  const int* __restrict__ ids, const float* __restrict__ wts,
                  const int* __restrict__ cnt, const int* __restrict__ offs,
                  float* __restrict__ out, int mode)
{
    extern __shared__ ushort lds[];
    int count;
    const ushort* BT; const float* bias; const int* toks; const float* tw;
    const ushort* Arows;
    if (mode == 1) {
        int e = blockIdx.z;
        count = cnt[e];
        BT    = ew2T + (size_t)e * DIM * HID;
        bias  = eb2 + e * DIM;
        toks  = ids + e * T_TOK;
        tw    = wts + e * T_TOK;
        Arows = h + (size_t)(T_TOK + offs[e]) * HID;
    } else {
        count = T_TOK; BT = sw2T; bias = sb2; toks = nullptr; tw = nullptr;
        Arows = h;
    }
    int tileM = blockIdx.y * 256, tileN = blockIdx.x * 256;
    if (tileM >= count) return;

    f32x4 acc[8][4];
#pragma unroll
    for (int m = 0; m < 8; ++m)
#pragma unroll
        for (int n = 0; n < 4; ++n) acc[m][n] = (f32x4){0.f, 0.f, 0.f, 0.f};

    mma256(Arows, nullptr, count, BT, HID, tileM, tileN, lds, acc);

    const int lane = threadIdx.x & 63, wave = threadIdx.x >> 6;
    const int wr = wave >> 2, wc = wave & 3, g = lane >> 4, fr = lane & 15;
#pragma unroll
    for (int n = 0; n < 4; ++n) {
        int col = tileN + wc * 64 + n * 16 + fr;
        float bc = bias[col];
#pragma unroll
        for (int m = 0; m < 8; ++m) {
#pragma unroll
            for (int i = 0; i < 4; ++i) {
                int row = tileM + wr * 128 + m * 16 + g * 4 + i;
                if (row < count) {
                    if (mode == 1) {
                        int token = toks[row];
                        float w   = tw[row];
                        atomicAdd(out + (size_t)token * DIM + col, w * (acc[m][n][i] + bc));
                    } else {
                        out[(size_t)row * DIM + col] = acc[m][n][i] + bc;
                    }
                }
            }
        }
    }
}

extern "C" void kernel_launch(void* const* d_in, const int* in_sizes, int n_in,
                              void* d_out, int out_size, void* d_ws, size_t ws_size,
                              hipStream_t stream)
{
    const float* x   = (const float*)d_in[0];
    const float* rw  = (const float*)d_in[1];
    const float* rb  = (const float*)d_in[2];
    const float* sw1 = (const float*)d_in[3];
    const float* sb1 = (const float*)d_in[4];
    const float* sw2 = (const float*)d_in[5];
    const float* sb2 = (const float*)d_in[6];
    const float* ew1 = (const float*)d_in[7];
    const float* eb1 = (const float*)d_in[8];
    const float* ew2 = (const float*)d_in[9];
    const float* eb2 = (const float*)d_in[10];
    float* out = (float*)d_out;

    char* p = (char*)d_ws;
    ushort* xb   = (ushort*)p;  p += (size_t)T_TOK * DIM * 2;
    ushort* sw1T = (ushort*)p;  p += (size_t)HID * DIM * 2;
    ushort* sw2T = (ushort*)p;  p += (size_t)DIM * HID * 2;
    ushort* ew1T = (ushort*)p;  p += (size_t)NE * HID * DIM * 2;
    ushort* ew2T = (ushort*)p;  p += (size_t)NE * DIM * HID * 2;
    ushort* hbuf = (ushort*)p;  p += (size_t)(3 * T_TOK) * HID * 2;
    int*    ids  = (int*)p;     p += (size_t)NE * T_TOK * 4;
    float*  wts  = (float*)p;   p += (size_t)NE * T_TOK * 4;
    int*    cnt  = (int*)p;     p += 256;
    int*    offs = (int*)p;     p += 256;

    hipFuncSetAttribute((const void*)gemm1_kernel,
                        hipFuncAttributeMaxDynamicSharedMemorySize, 131072);
    hipFuncSetAttribute((const void*)gemm2_kernel,
                        hipFuncAttributeMaxDynamicSharedMemorySize, 131072);

    hipMemsetAsync(cnt, 0, 256, stream);

    convert_x<<<dim3((T_TOK * DIM / 8 + 255) / 256), 256, 0, stream>>>(x, xb, T_TOK * DIM / 8);
    transpose_conv<<<dim3(HID / 32, DIM / 64, 1),  256, 0, stream>>>(sw1, sw1T, DIM, HID);
    transpose_conv<<<dim3(DIM / 32, HID / 64, 1),  256, 0, stream>>>(sw2, sw2T, HID, DIM);
    transpose_conv<<<dim3(HID / 32, DIM / 64, NE), 256, 0, stream>>>(ew1, ew1T, DIM, HID);
    transpose_conv<<<dim3(DIM / 32, HID / 64, NE), 256, 0, stream>>>(ew2, ew2T, HID, DIM);
    router_kernel<<<dim3(T_TOK / 4), 256, 0, stream>>>(x, rw, rb, cnt, ids, wts);
    offsets_kernel<<<dim3(1), 64, 0, stream>>>(cnt, offs);
    gemm1_kernel<<<dim3(HID / 256, T_TOK / 256, NE + 1), 512, 131072, stream>>>(
        xb, ew1T, sw1T, eb1, sb1, ids, cnt, offs, hbuf);
    gemm2_kernel<<<dim3(DIM / 256, T_TOK / 256, 1), 512, 131072, stream>>>(
        hbuf, ew2T, sw2T, eb2, sb2, ids, wts, cnt, offs, out, 0);
    gemm2_kernel<<<dim3(DIM / 256, T_TOK / 256, NE), 512, 131072, stream>>>(
        hbuf, ew2T, sw2T, eb2, sb2, ids, wts, cnt, offs, out, 1);
}

// Round 4
// 398.988 us; speedup vs baseline: 1.7062x; 1.7062x over previous
//
#include <hip/hip_runtime.h>

#define DIM   1024
#define HID   2048
#define NE    8
#define T_TOK 4096

typedef __attribute__((ext_vector_type(8))) short short8;
typedef __attribute__((ext_vector_type(4))) float f32x4;

__device__ __forceinline__ ushort f2bf(float f) {
    union { float f; unsigned u; } v; v.f = f;
    unsigned r = v.u + 0x7FFFu + ((v.u >> 16) & 1u);   // RNE
    return (ushort)(r >> 16);
}

__device__ __forceinline__ float gelu_exact(float x) {
    return 0.5f * x * (1.0f + erff(x * 0.70710678118654752f));
}

// ---------------- convert x (fp32 -> bf16) ----------------
__global__ void convert_x(const float* __restrict__ in, ushort* __restrict__ out, int n8) {
    int i = blockIdx.x * blockDim.x + threadIdx.x;
    if (i >= n8) return;
    const float4* p = (const float4*)in + (size_t)i * 2;
    float4 a = p[0], b = p[1];
    short8 o;
    o[0] = (short)f2bf(a.x); o[1] = (short)f2bf(a.y);
    o[2] = (short)f2bf(a.z); o[3] = (short)f2bf(a.w);
    o[4] = (short)f2bf(b.x); o[5] = (short)f2bf(b.y);
    o[6] = (short)f2bf(b.z); o[7] = (short)f2bf(b.w);
    *(short8*)(out + (size_t)i * 8) = o;
}

// ------- transpose+convert, 9 tensors in one launch: z<8 experts, z=8 shared -------
// in[R][C] f32 -> out[C][R] bf16. 32(C) x 64(R) tile; 128B contiguous bf16 writes.
__global__ void transpose_conv9(const float* __restrict__ ew, const float* __restrict__ sw,
                                ushort* __restrict__ ewT, ushort* __restrict__ swT,
                                int R, int C) {
    __shared__ float tile[32][65];
    int z = blockIdx.z;
    const float* in = (z < NE) ? ew + (size_t)z * R * C : sw;
    ushort* out     = (z < NE) ? ewT + (size_t)z * R * C : swT;
    int c0 = blockIdx.x * 32, r0 = blockIdx.y * 64;
    int tx = threadIdx.x & 31, ty = threadIdx.x >> 5;   // 256 threads
#pragma unroll
    for (int rr = 0; rr < 64; rr += 8)
        tile[tx][rr + ty] = in[(size_t)(r0 + rr + ty) * C + (c0 + tx)];
    __syncthreads();
    int lane = threadIdx.x & 63, q = threadIdx.x >> 6;
#pragma unroll
    for (int j = 0; j < 8; ++j) {
        int cc = q * 8 + j;
        out[(size_t)(c0 + cc) * R + (r0 + lane)] = f2bf(tile[cc][lane]);
    }
}

// ---------------- router: top-2 of softmax(x @ rw + rb), renormalized ----------------
__global__ void router_kernel(const float* __restrict__ x, const float* __restrict__ rw,
                              const float* __restrict__ rb, int* __restrict__ cnt,
                              int* __restrict__ ids, float* __restrict__ wts) {
    int wave = threadIdx.x >> 6;
    int lane = threadIdx.x & 63;
    int t = blockIdx.x * 4 + wave;
    const float* xr = x + (size_t)t * DIM;
    float acc[NE];
#pragma unroll
    for (int e = 0; e < NE; ++e) acc[e] = 0.f;
    for (int d = lane; d < DIM; d += 64) {
        float xv = xr[d];
#pragma unroll
        for (int e = 0; e < NE; ++e) acc[e] += xv * rw[d * NE + e];
    }
#pragma unroll
    for (int e = 0; e < NE; ++e) {
#pragma unroll
        for (int off = 32; off; off >>= 1) acc[e] += __shfl_xor(acc[e], off);
    }
    if (lane == 0) {
        float l[NE];
#pragma unroll
        for (int e = 0; e < NE; ++e) l[e] = acc[e] + rb[e];
        int i1 = 0;
#pragma unroll
        for (int e = 1; e < NE; ++e) if (l[e] > l[i1]) i1 = e;
        int i2 = (i1 == 0) ? 1 : 0;
#pragma unroll
        for (int e = 0; e < NE; ++e) if (e != i1 && l[e] > l[i2]) i2 = e;
        float p2 = __expf(l[i2] - l[i1]);      // p1 = 1
        float w1 = 1.0f / (1.0f + p2);
        float w2 = p2 / (1.0f + p2);
        int pos1 = atomicAdd(&cnt[i1], 1);
        ids[i1 * T_TOK + pos1] = t; wts[i1 * T_TOK + pos1] = w1;
        int pos2 = atomicAdd(&cnt[i2], 1);
        ids[i2 * T_TOK + pos2] = t; wts[i2 * T_TOK + pos2] = w2;
    }
}

__global__ void offsets_kernel(const int* __restrict__ cnt, int* __restrict__ offs) {
    if (threadIdx.x == 0) {
        int s = 0;
        for (int e = 0; e < NE; ++e) { offs[e] = s; s += cnt[e]; }
    }
}

// ===== 128x128 tile, BK=64, 4 waves, DOUBLE-BUFFERED LDS + COUNTED vmcnt =====
// LDS: 2 bufs x (A 128x64 + B 128x64) bf16 = 64 KiB -> 2 blocks/CU.
// Layout [row][64] with element-column XOR swizzle ((row&7)<<3), applied on the
// GLOBAL source column so global_load_lds destinations stay linear.
// Schedule (T4): STAGE(next) at phase top, then s_waitcnt vmcnt(8) — next tile's
// 8 loads stay in flight across the barrier and COMPUTE(cur). Raw s_barrier
// (not __syncthreads) so the compiler can't insert its own vmcnt(0) drain.
__device__ __forceinline__ void mma_tile(
    const ushort* __restrict__ A, const int* __restrict__ gather, int count,
    const ushort* __restrict__ BT, int K, int tileM, int tileN,
    ushort* lds, f32x4 acc[4][4])
{
    const int tid  = threadIdx.x;
    const int lane = tid & 63, wave = tid >> 6;
    const int wr = wave >> 1, wc = wave & 1;
    const int g = lane >> 4, fr = lane & 15;
    const int sub = lane >> 3;                     // row within 8-row chunk
    const int kcs = ((lane & 7) ^ sub) << 3;       // pre-swizzled global column

    const ushort* asrc[4];
    const ushort* bsrc[4];
#pragma unroll
    for (int i = 0; i < 4; ++i) {
        int row = (wave * 4 + i) * 8 + sub;        // 16 chunks cover 128 rows
        int ar = tileM + row; if (ar > count - 1) ar = count - 1;
        int grow = gather ? gather[ar] : ar;
        asrc[i] = A  + (size_t)grow * K + kcs;
        bsrc[i] = BT + (size_t)(tileN + row) * K + kcs;
    }

    auto STAGE = [&](int buf, int t) {
        ushort* base = lds + buf * 16384;          // A at +0, B at +8192 (elems)
#pragma unroll
        for (int i = 0; i < 4; ++i) {
            int chunk = wave * 4 + i;
            __builtin_amdgcn_global_load_lds(
                (const __attribute__((address_space(1))) void*)(asrc[i] + t * 64),
                (__attribute__((address_space(3))) void*)(base + chunk * 512),
                16, 0, 0);
            __builtin_amdgcn_global_load_lds(
                (const __attribute__((address_space(1))) void*)(bsrc[i] + t * 64),
                (__attribute__((address_space(3))) void*)(base + 8192 + chunk * 512),
                16, 0, 0);
        }
    };

    auto COMPUTE = [&](int buf) {
        const ushort* A_s = lds + buf * 16384;
        const ushort* B_s = A_s + 8192;
#pragma unroll
        for (int kk = 0; kk < 2; ++kk) {
            int koff = kk * 32 + g * 8;
            short8 a[4], b[4];
#pragma unroll
            for (int m = 0; m < 4; ++m) {
                int row = wr * 64 + m * 16 + fr;
                a[m] = *(const short8*)&A_s[row * 64 + (koff ^ ((row & 7) << 3))];
            }
#pragma unroll
            for (int n = 0; n < 4; ++n) {
                int col = wc * 64 + n * 16 + fr;
                b[n] = *(const short8*)&B_s[col * 64 + (koff ^ ((col & 7) << 3))];
            }
#pragma unroll
            for (int m = 0; m < 4; ++m)
#pragma unroll
                for (int n = 0; n < 4; ++n)
                    acc[m][n] = __builtin_amdgcn_mfma_f32_16x16x32_bf16(
                        a[m], b[n], acc[m][n], 0, 0, 0);
        }
    };

    const int NT = K >> 6;
    STAGE(0, 0);                                   // 8 loads out
    for (int t = 0; t < NT; ++t) {
        int cur = t & 1;
        if (t + 1 < NT) {
            STAGE(cur ^ 1, t + 1);                 // 16 out
            asm volatile("s_waitcnt vmcnt(8)" ::: "memory");   // tile t landed
        } else {
            asm volatile("s_waitcnt vmcnt(0)" ::: "memory");
        }
        __builtin_amdgcn_s_barrier();
        asm volatile("" ::: "memory");
        COMPUTE(cur);
        asm volatile("" ::: "memory");
        __builtin_amdgcn_s_barrier();              // buf[cur] free for overwrite
    }
}

// ---------------- GEMM1: h = gelu(X @ W1 + b1), packed per expert ----------------
__global__ __launch_bounds__(256)
void gemm1_kernel(const ushort* __restrict__ xb,
                  const ushort* __restrict__ ew1T, const ushort* __restrict__ sw1T,
                  const float* __restrict__ eb1, const float* __restrict__ sb1,
                  const int* __restrict__ ids, const int* __restrict__ cnt,
                  const int* __restrict__ offs, ushort* __restrict__ h)
{
    extern __shared__ ushort lds[];
    int e = blockIdx.z;
    int count, hbase;
    const ushort* BT; const float* bias; const int* gather;
    if (e < NE) {
        count  = cnt[e];
        BT     = ew1T + (size_t)e * HID * DIM;
        bias   = eb1 + e * HID;
        gather = ids + e * T_TOK;
        hbase  = T_TOK + offs[e];
    } else {
        count = T_TOK; BT = sw1T; bias = sb1; gather = nullptr; hbase = 0;
    }
    int tileM = blockIdx.y * 128, tileN = blockIdx.x * 128;
    if (tileM >= count) return;

    f32x4 acc[4][4];
#pragma unroll
    for (int m = 0; m < 4; ++m)
#pragma unroll
        for (int n = 0; n < 4; ++n) acc[m][n] = (f32x4){0.f, 0.f, 0.f, 0.f};

    mma_tile(xb, gather, count, BT, DIM, tileM, tileN, lds, acc);

    const int lane = threadIdx.x & 63, wave = threadIdx.x >> 6;
    const int wr = wave >> 1, wc = wave & 1, g = lane >> 4, fr = lane & 15;
#pragma unroll
    for (int n = 0; n < 4; ++n) {
        int col = tileN + wc * 64 + n * 16 + fr;
        float bc = bias[col];
#pragma unroll
        for (int m = 0; m < 4; ++m) {
#pragma unroll
            for (int i = 0; i < 4; ++i) {
                int row = tileM + wr * 64 + m * 16 + g * 4 + i;
                if (row < count)
                    h[(size_t)(hbase + row) * HID + col] =
                        f2bf(gelu_exact(acc[m][n][i] + bc));
            }
        }
    }
}

// ------- GEMM2 (single launch, all-atomic into pre-zeroed out): z<8 experts, z=8 shared -------
__global__ __launch_bounds__(256)
void gemm2_kernel(const ushort* __restrict__ h,
                  const ushort* __restrict__ ew2T, const ushort* __restrict__ sw2T,
                  const float* __restrict__ eb2, const float* __restrict__ sb2,
                  const int* __restrict__ ids, const float* __restrict__ wts,
                  const int* __restrict__ cnt, const int* __restrict__ offs,
                  float* __restrict__ out)
{
    extern __shared__ ushort lds[];
    int e = blockIdx.z;
    int count;
    const ushort* BT; const float* bias; const int* toks; const float* tw;
    const ushort* Arows;
    if (e < NE) {
        count = cnt[e];
        BT    = ew2T + (size_t)e * DIM * HID;
        bias  = eb2 + e * DIM;
        toks  = ids + e * T_TOK;
        tw    = wts + e * T_TOK;
        Arows = h + (size_t)(T_TOK + offs[e]) * HID;
    } else {
        count = T_TOK; BT = sw2T; bias = sb2; toks = nullptr; tw = nullptr;
        Arows = h;
    }
    int tileM = blockIdx.y * 128, tileN = blockIdx.x * 128;
    if (tileM >= count) return;

    f32x4 acc[4][4];
#pragma unroll
    for (int m = 0; m < 4; ++m)
#pragma unroll
        for (int n = 0; n < 4; ++n) acc[m][n] = (f32x4){0.f, 0.f, 0.f, 0.f};

    mma_tile(Arows, nullptr, count, BT, HID, tileM, tileN, lds, acc);

    const int lane = threadIdx.x & 63, wave = threadIdx.x >> 6;
    const int wr = wave >> 1, wc = wave & 1, g = lane >> 4, fr = lane & 15;
#pragma unroll
    for (int n = 0; n < 4; ++n) {
        int col = tileN + wc * 64 + n * 16 + fr;
        float bc = bias[col];
#pragma unroll
        for (int m = 0; m < 4; ++m) {
#pragma unroll
            for (int i = 0; i < 4; ++i) {
                int row = tileM + wr * 64 + m * 16 + g * 4 + i;
                if (row < count) {
                    int token = toks ? toks[row] : row;
                    float w   = tw ? tw[row] : 1.0f;
                    atomicAdd(out + (size_t)token * DIM + col, w * (acc[m][n][i] + bc));
                }
            }
        }
    }
}

extern "C" void kernel_launch(void* const* d_in, const int* in_sizes, int n_in,
                              void* d_out, int out_size, void* d_ws, size_t ws_size,
                              hipStream_t stream)
{
    const float* x   = (const float*)d_in[0];
    const float* rw  = (const float*)d_in[1];
    const float* rb  = (const float*)d_in[2];
    const float* sw1 = (const float*)d_in[3];
    const float* sb1 = (const float*)d_in[4];
    const float* sw2 = (const float*)d_in[5];
    const float* sb2 = (const float*)d_in[6];
    const float* ew1 = (const float*)d_in[7];
    const float* eb1 = (const float*)d_in[8];
    const float* ew2 = (const float*)d_in[9];
    const float* eb2 = (const float*)d_in[10];
    float* out = (float*)d_out;

    char* p = (char*)d_ws;
    ushort* xb   = (ushort*)p;  p += (size_t)T_TOK * DIM * 2;
    ushort* sw1T = (ushort*)p;  p += (size_t)HID * DIM * 2;
    ushort* sw2T = (ushort*)p;  p += (size_t)DIM * HID * 2;
    ushort* ew1T = (ushort*)p;  p += (size_t)NE * HID * DIM * 2;
    ushort* ew2T = (ushort*)p;  p += (size_t)NE * DIM * HID * 2;
    ushort* hbuf = (ushort*)p;  p += (size_t)(3 * T_TOK) * HID * 2;
    int*    ids  = (int*)p;     p += (size_t)NE * T_TOK * 4;
    float*  wts  = (float*)p;   p += (size_t)NE * T_TOK * 4;
    int*    cnt  = (int*)p;     p += 256;
    int*    offs = (int*)p;     p += 256;

    hipFuncSetAttribute((const void*)gemm1_kernel,
                        hipFuncAttributeMaxDynamicSharedMemorySize, 65536);
    hipFuncSetAttribute((const void*)gemm2_kernel,
                        hipFuncAttributeMaxDynamicSharedMemorySize, 65536);

    hipMemsetAsync(cnt, 0, 256, stream);
    hipMemsetAsync(out, 0, (size_t)out_size * 4, stream);

    convert_x<<<dim3((T_TOK * DIM / 8 + 255) / 256), 256, 0, stream>>>(x, xb, T_TOK * DIM / 8);
    transpose_conv9<<<dim3(HID / 32, DIM / 64, NE + 1), 256, 0, stream>>>(
        ew1, sw1, ew1T, sw1T, DIM, HID);
    transpose_conv9<<<dim3(DIM / 32, HID / 64, NE + 1), 256, 0, stream>>>(
        ew2, sw2, ew2T, sw2T, HID, DIM);
    router_kernel<<<dim3(T_TOK / 4), 256, 0, stream>>>(x, rw, rb, cnt, ids, wts);
    offsets_kernel<<<dim3(1), 64, 0, stream>>>(cnt, offs);
    gemm1_kernel<<<dim3(HID / 128, T_TOK / 128, NE + 1), 256, 65536, stream>>>(
        xb, ew1T, sw1T, eb1, sb1, ids, cnt, offs, hbuf);
    gemm2_kernel<<<dim3(DIM / 128, T_TOK / 128, NE + 1), 256, 65536, stream>>>(
        hbuf, ew2T, sw2T, eb2, sb2, ids, wts, cnt, offs, out);
}